// Round 9
// baseline (303.716 us; speedup 1.0000x reference)
//
#include <hip/hip_runtime.h>
#include <hip/hip_bf16.h>

#define NE 4
#define HD 768
#define F2 384
#define F1 192
#define NT 131072
#define TT 64

typedef __attribute__((ext_vector_type(8))) short bf16x8;
typedef __attribute__((ext_vector_type(4))) float f32x4;
typedef __attribute__((ext_vector_type(4))) unsigned int u32x4;
typedef __attribute__((ext_vector_type(2))) unsigned int u32x2;

// LDS layout (bytes), 73984 total -> 2 blocks/CU:
//  GEMM1: A dbuf [0,9216) (64 rows x 72B, x2) ; B1 dbuf [9216,58368) (2 x 24K)
//  GU   : gate/up bf16 [24576,73728) (64 x 768B)   (after GEMM1)
//  GEMM2: act [0,24576) (64 x 384B) ; B2 dbuf [24576,73728) (2 x 24K)
//  tok  : [73728,73984)
#define LAB0 0u
#define LAB1 4608u
#define LB10 9216u
#define LB11 33792u
#define LGU  24576u
#define LACT 0u
#define LC0  24576u
#define LC1  49152u
#define LTOK 73728u
#define SMEM_BYTES 73984

// workspace layout (bytes)
#define WS_BUCKET_OFF 256
#define WS_B1IMG_OFF (WS_BUCKET_OFF + NE*NT*4)            // B1 image: NE*24*24576 = 2.36 MB
#define WS_DNIMG_OFF (WS_B1IMG_OFF + NE*24*24576)         // B2 image: NE*2*6*24576 = 1.18 MB
// b1img: per (e,kstep) a 24KB LDS byte-image, 16B unit L: colp=L>>3, slot=L&7,
//        v=slot^(colp&7), tilecol=colp*2+(v>>2), k=kstep*32+(v&3)*8
// dnimg: per (e,half,kt) a 24KB image, same unit mapping; col=h within half, k over 192

__device__ __forceinline__ unsigned short f2bf(float x) {
    unsigned int u = __float_as_uint(x);
    return (unsigned short)((u + 0x7fffu + ((u >> 16) & 1u)) >> 16);
}
__device__ __forceinline__ unsigned int pk2(float a, float b) {
    unsigned int ua = __float_as_uint(a), ub = __float_as_uint(b);
    unsigned int lo = (ua + 0x7fffu + ((ua >> 16) & 1u)) >> 16;
    unsigned int hi = (ub + 0x7fffu + ((ub >> 16) & 1u)) & 0xffff0000u;
    return lo | hi;
}
__device__ __forceinline__ float bf2f(unsigned short s) {
    return __uint_as_float(((unsigned int)s) << 16);
}
#define GLL(srcp, ldsoff) \
    __builtin_amdgcn_global_load_lds((const __attribute__((address_space(1))) void*)(srcp), \
        (__attribute__((address_space(3))) void*)(smem + (ldsoff)), 16, 0, 0)

__global__ void route_kernel(const int* __restrict__ ids, int* __restrict__ counts,
                             int* __restrict__ bucket) {
    __shared__ int lc[NE];
    __shared__ int lb[NE];
    int tid = threadIdx.x;
    if (tid < NE) lc[tid] = 0;
    __syncthreads();
    int t = blockIdx.x * blockDim.x + tid;
    int e = ids[t];
    int rank = atomicAdd(&lc[e], 1);
    __syncthreads();
    if (tid < NE) lb[tid] = atomicAdd(&counts[tid], lc[tid]);
    __syncthreads();
    bucket[e * NT + lb[e] + rank] = t;
}

// Build the pre-swizzled B1 LDS image: one thread per 16B unit.
__global__ void b1img_kernel(const float* __restrict__ gu, unsigned short* __restrict__ b1img) {
    int idx = blockIdx.x * 256 + threadIdx.x;      // NE*24*1536 = 147456
    int L = idx % 1536;
    int es = idx / 1536;
    int kstep = es % 24, e = es / 24;
    int colp = L >> 3, slot = L & 7;
    int v = slot ^ (colp & 7);
    int tc = colp * 2 + (v >> 2);
    int kb = kstep * 32 + (v & 3) * 8;
    const float* src = gu + ((size_t)(e * HD + kb)) * F2 + tc;
    unsigned short o[8];
    #pragma unroll
    for (int j = 0; j < 8; ++j) o[j] = f2bf(src[(size_t)j * F2]);
    *(bf16x8*)(b1img + ((size_t)idx) * 8) = *(const bf16x8*)o;
}

// Build the pre-swizzled B2 (down-proj) LDS image: one thread per 16B unit.
__global__ void dnimg_kernel(const float* __restrict__ dn, unsigned short* __restrict__ dnimg) {
    int idx = blockIdx.x * 256 + threadIdx.x;      // NE*2*6*1536 = 73728
    int L = idx % 1536;
    int r = idx / 1536;
    int kt = r % 6; r /= 6;
    int half = r & 1; int e = r >> 1;
    int colp = L >> 3, slot = L & 7;
    int v = slot ^ (colp & 7);
    int tc = colp * 2 + (v >> 2);                  // h-col within half (0..383)
    int kb = kt * 32 + (v & 3) * 8;                // f-index (0..191)
    const float* src = dn + ((size_t)(e * F1 + kb)) * HD + half * 384 + tc;
    unsigned short o[8];
    #pragma unroll
    for (int j = 0; j < 8; ++j) o[j] = f2bf(src[(size_t)j * HD]);
    *(bf16x8*)(dnimg + ((size_t)idx) * 8) = *(const bf16x8*)o;
}

__global__ __launch_bounds__(512, 2)
void moe_kernel(const float* __restrict__ hidden, const int* __restrict__ counts,
                const int* __restrict__ bucket, const unsigned short* __restrict__ b1img,
                const unsigned short* __restrict__ dnimg, float* __restrict__ out)
{
    extern __shared__ __align__(16) unsigned char smem[];

    // block -> (expert, tile) via prefix over counts, TT=64
    int rem = blockIdx.x, e, n_e = 0;
    for (e = 0; e < NE; ++e) {
        n_e = counts[e];
        int ntiles = (n_e + TT - 1) >> 6;
        if (rem < ntiles) break;
        rem -= ntiles;
    }
    if (e >= NE) return;
    int t0 = rem << 6;

    int tid = threadIdx.x;
    int lane = tid & 63;
    int w = tid >> 6;              // wave 0..7: 48 cols each of the 384
    int lg = lane >> 4;
    int l16 = lane & 15;

    int* tokp = (int*)(smem + LTOK);
    if (tid < TT) {
        int idx = t0 + tid; if (idx >= n_e) idx = n_e - 1;
        tokp[tid] = bucket[e * NT + idx];
    }
    __syncthreads();

    // ---- A staging: thread -> (row=tid>>3, kq=tid&7), 4 fp32 per step ----
    int ar = tid >> 3, kq = tid & 7;
    const float* aptr = hidden + (size_t)tokp[ar] * HD + kq * 4;
    unsigned awb = (unsigned)(ar * 72 + (((kq >> 1) ^ (ar & 3)) << 4) + (kq & 1) * 8);

    // ---- B1/B2 GLL: 3 wave-loads/step from pre-swizzled images ----
    const unsigned short* gls  = b1img + (size_t)e * 24 * 12288 + (w * 3) * 512 + lane * 8;
    const unsigned short* gls2 = dnimg + (size_t)e * 12 * 12288 + (w * 3) * 512 + lane * 8;
    unsigned gld = (unsigned)(w * 3) * 1024u;

    // ---- fragment read addressing ----
    // A-frag: row=mt*16+l16 (stride 72B, (r&3)-XOR on k-slot)
    unsigned arb[4];
    #pragma unroll
    for (int mt = 0; mt < 4; ++mt)
        arb[mt] = (unsigned)((mt * 16 + l16) * 72 + ((lg ^ (l16 & 3)) << 4));
    // B-frag: slot-XOR image layout (proven 0-conflict)
    unsigned laneoff = (unsigned)(((l16 >> 1) << 7) +
                       (((lg + ((l16 & 1) << 2)) ^ (l16 >> 1)) << 4));
    unsigned brb[3];
    #pragma unroll
    for (int nt = 0; nt < 3; ++nt)
        brb[nt] = (unsigned)((w * 48 + nt * 16) * 64) + laneoff;

    f32x4 av;
    auto issueA = [&](int g) { av = *(const f32x4*)(aptr + g * 32); };
    auto writeA = [&](unsigned base) {
        u32x2 vv = {pk2(av.x, av.y), pk2(av.z, av.w)};
        *(u32x2*)(smem + base + awb) = vv;
    };

    const f32x4 fzero = {0.f, 0.f, 0.f, 0.f};
    f32x4 acc[4][3];
    #pragma unroll
    for (int mt = 0; mt < 4; ++mt)
        #pragma unroll
        for (int nt = 0; nt < 3; ++nt) acc[mt][nt] = fzero;

    // ================= GEMM1: C1[64][384], K=768, BK=32, 1-deep dbuf =================
    issueA(0);
    #pragma unroll
    for (int i = 0; i < 3; ++i) GLL(gls + i * 512, LB10 + gld + i * 1024u);
    writeA(LAB0);
    asm volatile("s_waitcnt vmcnt(0) lgkmcnt(0)");
    __builtin_amdgcn_s_barrier();
    __builtin_amdgcn_sched_barrier(0);

    #pragma unroll 1
    for (int g = 0; g < 24; ++g) {
        unsigned Ab  = (g & 1) ? LAB1 : LAB0;
        unsigned Bb  = (g & 1) ? LB11 : LB10;
        unsigned Abn = (g & 1) ? LAB0 : LAB1;
        unsigned Bbn = (g & 1) ? LB10 : LB11;
        if (g < 23) {
            issueA(g + 1);
            #pragma unroll
            for (int i = 0; i < 3; ++i)
                GLL(gls + (size_t)(g + 1) * 12288 + i * 512, Bbn + gld + i * 1024u);
        }

        bf16x8 Af[4];
        #pragma unroll
        for (int mt = 0; mt < 4; ++mt)
            Af[mt] = *(const bf16x8*)(smem + Ab + arb[mt]);
        __builtin_amdgcn_s_setprio(1);
        #pragma unroll
        for (int nt = 0; nt < 3; ++nt) {
            bf16x8 Bf = *(const bf16x8*)(smem + Bb + brb[nt]);
            #pragma unroll
            for (int mt = 0; mt < 4; ++mt)
                acc[mt][nt] = __builtin_amdgcn_mfma_f32_16x16x32_bf16(Af[mt], Bf, acc[mt][nt], 0, 0, 0);
        }
        __builtin_amdgcn_s_setprio(0);

        if (g < 23) writeA(Abn);
        asm volatile("s_waitcnt vmcnt(0) lgkmcnt(0)");
        __builtin_amdgcn_s_barrier();
        __builtin_amdgcn_sched_barrier(0);
    }

    // ================= gate/up -> GU LDS (bf16), then act = silu(g)*u =================
    // wave w owns vcols [w*48, w*48+48): w<4 -> gate f, w>=4 -> up f (vcol-192)
    #pragma unroll
    for (int mt = 0; mt < 4; ++mt)
        #pragma unroll
        for (int nt = 0; nt < 3; ++nt)
            #pragma unroll
            for (int p = 0; p < 4; ++p) {
                int row = mt * 16 + 4 * lg + p;
                int vc = w * 48 + nt * 16 + l16;
                int c = vc >> 3;
                unsigned b = (unsigned)(LGU + row * 768 +
                             (((c & ~7) | ((c & 7) ^ (row & 7))) << 4) + (vc & 7) * 2);
                *(unsigned short*)(smem + b) = f2bf(acc[mt][nt][p]);
            }
    asm volatile("s_waitcnt lgkmcnt(0)");
    __builtin_amdgcn_s_barrier();

    // act: thread -> row r=tid>>3, f-group q=tid&7 (chunks q*3..q*3+2)
    {
        int r = tid >> 3, q = tid & 7;
        #pragma unroll
        for (int j3 = 0; j3 < 3; ++j3) {
            int c = q * 3 + j3;
            unsigned gb = (unsigned)(LGU + r * 768 + (((c & ~7) | ((c & 7) ^ (r & 7))) << 4));
            bf16x8 gv = *(const bf16x8*)(smem + gb);
            bf16x8 uv = *(const bf16x8*)(smem + gb + 384u);
            unsigned int o[4];
            #pragma unroll
            for (int j = 0; j < 4; ++j) {
                float g0 = bf2f((unsigned short)gv[2 * j]);
                float g1 = bf2f((unsigned short)gv[2 * j + 1]);
                float u0 = bf2f((unsigned short)uv[2 * j]);
                float u1 = bf2f((unsigned short)uv[2 * j + 1]);
                float a0 = g0 / (1.f + __expf(-g0)) * u0;
                float a1 = g1 / (1.f + __expf(-g1)) * u1;
                o[j] = pk2(a0, a1);
            }
            unsigned ab = (unsigned)(LACT + r * 384 + (((c & ~7) | ((c & 7) ^ (r & 7))) << 4));
            *(u32x4*)(smem + ab) = *(u32x4*)o;
        }
    }
    asm volatile("s_waitcnt lgkmcnt(0)");
    __builtin_amdgcn_s_barrier();
    __builtin_amdgcn_sched_barrier(0);

    // ================= GEMM2: out[64][768] = act[64][192] * down, 1-deep dbuf =================
    #pragma unroll
    for (int i = 0; i < 3; ++i) GLL(gls2 + i * 512, LC0 + gld + i * 1024u);
    asm volatile("s_waitcnt vmcnt(0)");
    __builtin_amdgcn_s_barrier();
    __builtin_amdgcn_sched_barrier(0);

    #pragma unroll
    for (int half = 0; half < 2; ++half) {
        f32x4 c2[4][3];
        #pragma unroll
        for (int mt = 0; mt < 4; ++mt)
            #pragma unroll
            for (int nt = 0; nt < 3; ++nt) c2[mt][nt] = fzero;

        #pragma unroll
        for (int kt = 0; kt < 6; ++kt) {
            const int s = half * 6 + kt;
            unsigned Cb = (s & 1) ? LC1 : LC0;
            if (s < 11) {
                unsigned Cbn = (s & 1) ? LC0 : LC1;
                #pragma unroll
                for (int i = 0; i < 3; ++i)
                    GLL(gls2 + (size_t)(s + 1) * 12288 + i * 512, Cbn + gld + i * 1024u);
            }

            int c = kt * 4 + lg;
            unsigned a2sl = (unsigned)((((c & 24) | ((c & 7) ^ (l16 & 7)))) << 4);
            bf16x8 A2[4];
            #pragma unroll
            for (int mt = 0; mt < 4; ++mt)
                A2[mt] = *(const bf16x8*)(smem + LACT + (mt * 16 + l16) * 384 + a2sl);
            __builtin_amdgcn_s_setprio(1);
            #pragma unroll
            for (int nt = 0; nt < 3; ++nt) {
                bf16x8 B2f = *(const bf16x8*)(smem + Cb + brb[nt] - (unsigned)0); // col base w*48+nt*16
                #pragma unroll
                for (int mt = 0; mt < 4; ++mt)
                    c2[mt][nt] = __builtin_amdgcn_mfma_f32_16x16x32_bf16(A2[mt], B2f, c2[mt][nt], 0, 0, 0);
            }
            __builtin_amdgcn_s_setprio(0);

            if (s < 11) {
                asm volatile("s_waitcnt vmcnt(0) lgkmcnt(0)");
                __builtin_amdgcn_s_barrier();
                __builtin_amdgcn_sched_barrier(0);
            }
        }

        #pragma unroll
        for (int mt = 0; mt < 4; ++mt)
            #pragma unroll
            for (int p = 0; p < 4; ++p) {
                int row = mt * 16 + 4 * lg + p;
                if (t0 + row < n_e) {
                    float* orow = out + (size_t)tokp[row] * HD + half * 384 + w * 48 + l16;
                    #pragma unroll
                    for (int nt = 0; nt < 3; ++nt)
                        orow[nt * 16] = c2[mt][nt][p];
                }
            }
    }
}

extern "C" void kernel_launch(void* const* d_in, const int* in_sizes, int n_in,
                              void* d_out, int out_size, void* d_ws, size_t ws_size,
                              hipStream_t stream) {
    (void)in_sizes; (void)n_in; (void)out_size; (void)ws_size;
    const float* hidden = (const float*)d_in[0];
    const int*   ids    = (const int*)d_in[1];
    const float* gu     = (const float*)d_in[2];
    const float* dn     = (const float*)d_in[3];
    float* out = (float*)d_out;

    char* ws = (char*)d_ws;
    int* counts = (int*)ws;
    int* bucket = (int*)(ws + WS_BUCKET_OFF);
    unsigned short* b1img = (unsigned short*)(ws + WS_B1IMG_OFF);
    unsigned short* dnimg = (unsigned short*)(ws + WS_DNIMG_OFF);

    hipMemsetAsync(d_ws, 0, 64, stream);
    route_kernel<<<NT / 256, 256, 0, stream>>>(ids, counts, bucket);
    b1img_kernel<<<576, 256, 0, stream>>>(gu, b1img);       // NE*24*1536 units
    dnimg_kernel<<<288, 256, 0, stream>>>(dn, dnimg);       // NE*2*6*1536 units
    // max blocks = sum of per-expert ceils <= 2048 + 3
    moe_kernel<<<2052, 512, SMEM_BYTES, stream>>>(hidden, counts, bucket, b1img, dnimg, out);
}

// Round 10
// 283.480 us; speedup vs baseline: 1.0714x; 1.0714x over previous
//
#include <hip/hip_runtime.h>
#include <hip/hip_bf16.h>

#define NE 4
#define HD 768
#define F2 384
#define F1 192
#define NT 131072
#define TT 128

typedef __attribute__((ext_vector_type(8))) short bf16x8;
typedef __attribute__((ext_vector_type(4))) float f32x4;
typedef __attribute__((ext_vector_type(4))) unsigned int u32x4;

// LDS layout (bytes):
//  GEMM1: A dbuf 0..16K ; B1 quad-buf 16K..112K (4 x 24K)
//  GEMM2: act 0..48K (overlays A + B1[0..1]) ; B2 tri-buf 48K..120K (3 x 24K)
//  tok 120K.. (survives whole kernel)
#define SMEM_BYTES 123392
#define LTOK 122880u

// workspace layout (bytes)
#define WS_BUCKET_OFF 256
#define WS_B1IMG_OFF (WS_BUCKET_OFF + NE*NT*4)            // B1 image: NE*24*24576 = 2.36 MB
#define WS_DNIMG_OFF (WS_B1IMG_OFF + NE*24*24576)         // B2 image: NE*2*6*24576 = 1.18 MB
// b1img: per (e,kstep) a 24KB LDS byte-image, 16B unit L: colp=L>>3, slot=L&7,
//        v=slot^(colp&7), tilecol=colp*2+(v>>2), k=kstep*32+(v&3)*8
// dnimg: per (e,half,kt) a 24KB image, same unit mapping; col=h within half, k over 192

__device__ __forceinline__ unsigned short f2bf(float x) {
    unsigned int u = __float_as_uint(x);
    return (unsigned short)((u + 0x7fffu + ((u >> 16) & 1u)) >> 16);
}
__device__ __forceinline__ unsigned int pk2(float a, float b) {
    unsigned int ua = __float_as_uint(a), ub = __float_as_uint(b);
    unsigned int lo = (ua + 0x7fffu + ((ua >> 16) & 1u)) >> 16;
    unsigned int hi = (ub + 0x7fffu + ((ub >> 16) & 1u)) & 0xffff0000u;
    return lo | hi;
}
#define GLL(srcp, ldsoff) \
    __builtin_amdgcn_global_load_lds((const __attribute__((address_space(1))) void*)(srcp), \
        (__attribute__((address_space(3))) void*)(smem + (ldsoff)), 16, 0, 0)

__global__ void route_kernel(const int* __restrict__ ids, int* __restrict__ counts,
                             int* __restrict__ bucket) {
    __shared__ int lc[NE];
    __shared__ int lb[NE];
    int tid = threadIdx.x;
    if (tid < NE) lc[tid] = 0;
    __syncthreads();
    int t = blockIdx.x * blockDim.x + tid;
    int e = ids[t];
    int rank = atomicAdd(&lc[e], 1);
    __syncthreads();
    if (tid < NE) lb[tid] = atomicAdd(&counts[tid], lc[tid]);
    __syncthreads();
    bucket[e * NT + lb[e] + rank] = t;
}

// Build the pre-swizzled B1 LDS image: one thread per 16B unit.
__global__ void b1img_kernel(const float* __restrict__ gu, unsigned short* __restrict__ b1img) {
    int idx = blockIdx.x * 256 + threadIdx.x;      // NE*24*1536 = 147456
    int L = idx % 1536;
    int es = idx / 1536;
    int kstep = es % 24, e = es / 24;
    int colp = L >> 3, slot = L & 7;
    int v = slot ^ (colp & 7);
    int tc = colp * 2 + (v >> 2);
    int kb = kstep * 32 + (v & 3) * 8;
    const float* src = gu + ((size_t)(e * HD + kb)) * F2 + tc;
    unsigned short o[8];
    #pragma unroll
    for (int j = 0; j < 8; ++j) o[j] = f2bf(src[(size_t)j * F2]);
    *(bf16x8*)(b1img + ((size_t)idx) * 8) = *(const bf16x8*)o;
}

// Build the pre-swizzled B2 (down-proj) LDS image: one thread per 16B unit.
__global__ void dnimg_kernel(const float* __restrict__ dn, unsigned short* __restrict__ dnimg) {
    int idx = blockIdx.x * 256 + threadIdx.x;      // NE*2*6*1536 = 73728
    int L = idx % 1536;
    int r = idx / 1536;
    int kt = r % 6; r /= 6;
    int half = r & 1; int e = r >> 1;
    int colp = L >> 3, slot = L & 7;
    int v = slot ^ (colp & 7);
    int tc = colp * 2 + (v >> 2);                  // h-col within half (0..383)
    int kb = kt * 32 + (v & 3) * 8;                // f-index (0..191)
    const float* src = dn + ((size_t)(e * F1 + kb)) * HD + half * 384 + tc;
    unsigned short o[8];
    #pragma unroll
    for (int j = 0; j < 8; ++j) o[j] = f2bf(src[(size_t)j * HD]);
    *(bf16x8*)(dnimg + ((size_t)idx) * 8) = *(const bf16x8*)o;
}

__global__ __launch_bounds__(512, 1)
void moe_kernel(const float* __restrict__ hidden, const int* __restrict__ counts,
                const int* __restrict__ bucket, const unsigned short* __restrict__ b1img,
                const unsigned short* __restrict__ dnimg, float* __restrict__ out)
{
    extern __shared__ __align__(16) unsigned char smem[];
    const unsigned LAo[2] = {0u, 8192u};
    const unsigned LBo[4] = {16384u, 40960u, 65536u, 90112u};
    const unsigned LCo[3] = {49152u, 73728u, 98304u};
    const unsigned LACT = 0u;

    // exact block -> (expert, tile) mapping via prefix over counts
    int rem = blockIdx.x, e, n_e = 0;
    for (e = 0; e < NE; ++e) {
        n_e = counts[e];
        int ntiles = (n_e + TT - 1) >> 7;
        if (rem < ntiles) break;
        rem -= ntiles;
    }
    if (e >= NE) return;
    int t0 = rem << 7;

    int tid = threadIdx.x;
    int lane = tid & 63;
    int w = tid >> 6;
    int rw64 = (w >> 2) << 6;      // row half 0/64
    int cq = w & 3;                // col quarter
    int lg = lane >> 4;
    int l16 = lane & 15;

    int* tokp = (int*)(smem + LTOK);
    if (tid < TT) {
        int idx = t0 + tid; if (idx >= n_e) idx = n_e - 1;
        tokp[tid] = bucket[e * NT + idx];
    }
    __syncthreads();

    // ---- A staging: thread -> (row=tid>>2, kq=tid&3), 8 fp32 per step ----
    int arow = tid >> 2, kq = tid & 3;
    const float* aptr = hidden + (size_t)tokp[arow] * HD + kq * 8;
    unsigned awb = (unsigned)((tid >> 3) * 128 +
                   (((kq + ((arow & 1) << 2)) ^ ((tid >> 3) & 7)) << 4));

    // ---- B1 / B2 GLL: 3 wave-loads/step from pre-swizzled images ----
    const unsigned short* gls  = b1img + (size_t)e * 24 * 12288 + (w * 3) * 512 + lane * 8;
    const unsigned short* gls2 = dnimg + (size_t)e * 12 * 12288 + (w * 3) * 512 + lane * 8;
    unsigned gld = (unsigned)(w * 3) * 1024u;

    // ---- fragment read addressing (slot-XOR, proven 0-conflict) ----
    unsigned laneoff = (unsigned)(((l16 >> 1) << 7) +
                       (((lg + ((l16 & 1) << 2)) ^ (l16 >> 1)) << 4));
    unsigned arb[4], brb[6], b2rb[6];
    #pragma unroll
    for (int mt = 0; mt < 4; ++mt)
        arb[mt] = (unsigned)((rw64 + mt * 16) * 64) + laneoff;
    #pragma unroll
    for (int nt = 0; nt < 6; ++nt) {
        int tcb = (nt < 3) ? (cq * 48 + nt * 16) : (192 + cq * 48 + (nt - 3) * 16);
        brb[nt] = (unsigned)(tcb * 64) + laneoff;
        b2rb[nt] = (unsigned)((cq * 96 + nt * 16) * 64) + laneoff;
    }

    f32x4 avb[4][2];               // A register ring, depth 4
    const f32x4 fzero = {0.f, 0.f, 0.f, 0.f};
    f32x4 acc[4][6];
    #pragma unroll
    for (int mt = 0; mt < 4; ++mt)
        #pragma unroll
        for (int nt = 0; nt < 6; ++nt) acc[mt][nt] = fzero;

    // ================= GEMM1: C1[128][384], K=768, BK=32, 3-deep B + 4-deep A =================
    // prologue issue order: B(0), A(0..3), B(1), B(2); then writeA(0)
    {
        #pragma unroll
        for (int i = 0; i < 3; ++i) GLL(gls + i * 512, LBo[0] + gld + i * 1024u);
        #pragma unroll
        for (int j = 0; j < 4; ++j) {
            const f32x4* p = (const f32x4*)(aptr + j * 32);
            avb[j][0] = p[0]; avb[j][1] = p[1];
        }
        #pragma unroll
        for (int i = 0; i < 3; ++i) GLL(gls + 12288 + i * 512, LBo[1] + gld + i * 1024u);
        #pragma unroll
        for (int i = 0; i < 3; ++i) GLL(gls + 2 * 12288 + i * 512, LBo[2] + gld + i * 1024u);
        // writeA(0): compiler inserts a counted vmcnt covering A(0) only
        u32x4 vv = {pk2(avb[0][0].x,avb[0][0].y), pk2(avb[0][0].z,avb[0][0].w),
                    pk2(avb[0][1].x,avb[0][1].y), pk2(avb[0][1].z,avb[0][1].w)};
        *(u32x4*)(smem + LAo[0] + awb) = vv;
        asm volatile("s_waitcnt vmcnt(14) lgkmcnt(0)");   // B(0) done; A(1..3),B(1),B(2) in flight
        __builtin_amdgcn_s_barrier();
        __builtin_amdgcn_sched_barrier(0);
    }

    #pragma unroll
    for (int g = 0; g < 24; ++g) {
        // issue B(g+3) first, then A(g+4): keeps deep A newer than the B we wait on
        if (g < 21) {
            #pragma unroll
            for (int i = 0; i < 3; ++i)
                GLL(gls + (size_t)(g + 3) * 12288 + i * 512, LBo[(g + 3) & 3] + gld + i * 1024u);
        }
        if (g < 20) {
            const f32x4* p = (const f32x4*)(aptr + (g + 4) * 32);
            avb[g & 3][0] = p[0]; avb[g & 3][1] = p[1];   // (g+4)&3 == g&3
        }

        // compute step g from LA[g&1], LB[g&3]
        bf16x8 Af[4];
        #pragma unroll
        for (int mt = 0; mt < 4; ++mt)
            Af[mt] = *(const bf16x8*)(smem + LAo[g & 1] + arb[mt]);
        __builtin_amdgcn_s_setprio(1);
        #pragma unroll
        for (int nt = 0; nt < 6; ++nt) {
            bf16x8 Bf = *(const bf16x8*)(smem + LBo[g & 3] + brb[nt]);
            #pragma unroll
            for (int mt = 0; mt < 4; ++mt)
                acc[mt][nt] = __builtin_amdgcn_mfma_f32_16x16x32_bf16(Af[mt], Bf, acc[mt][nt], 0, 0, 0);
        }
        __builtin_amdgcn_s_setprio(0);

        if (g < 23) {
            // writeA(g+1): consumes avb[(g+1)&3] = A(g+1), loaded 4 steps ago
            f32x4 a0 = avb[(g + 1) & 3][0], a1 = avb[(g + 1) & 3][1];
            u32x4 vv = {pk2(a0.x,a0.y), pk2(a0.z,a0.w), pk2(a1.x,a1.y), pk2(a1.z,a1.w)};
            *(u32x4*)(smem + LAo[(g + 1) & 1] + awb) = vv;
            // boundary: require B(g+1) complete; allow 2 full steps + A(g+2) in flight
            if (g == 0)       asm volatile("s_waitcnt vmcnt(8) lgkmcnt(0)");
            else if (g == 1)  asm volatile("s_waitcnt vmcnt(10) lgkmcnt(0)");
            else if (g <= 19) asm volatile("s_waitcnt vmcnt(12) lgkmcnt(0)");
            else if (g == 20) asm volatile("s_waitcnt vmcnt(10) lgkmcnt(0)");
            else if (g == 21) asm volatile("s_waitcnt vmcnt(5) lgkmcnt(0)");
            else              asm volatile("s_waitcnt vmcnt(0) lgkmcnt(0)");
            __builtin_amdgcn_s_barrier();
            __builtin_amdgcn_sched_barrier(0);
        }
    }

    // barrier: all waves done reading B1/A before act overwrites those regions
    asm volatile("s_waitcnt vmcnt(0) lgkmcnt(0)");
    __builtin_amdgcn_s_barrier();
    __builtin_amdgcn_sched_barrier(0);

    // ================= act = silu(gate)*up -> LDS ; prefetch B2(0),B2(1) =================
    #pragma unroll
    for (int i = 0; i < 3; ++i) GLL(gls2 + i * 512, LCo[0] + gld + i * 1024u);
    #pragma unroll
    for (int i = 0; i < 3; ++i) GLL(gls2 + 12288 + i * 512, LCo[1] + gld + i * 1024u);

    #pragma unroll
    for (int mt = 0; mt < 4; ++mt)
        #pragma unroll
        for (int nt = 0; nt < 3; ++nt)
            #pragma unroll
            for (int p = 0; p < 4; ++p) {
                float g = acc[mt][nt][p];
                float u = acc[mt][nt + 3][p];
                float s = g / (1.f + __expf(-g));
                int row = rw64 + mt * 16 + 4 * lg + p;
                int f = cq * 48 + nt * 16 + l16;
                int c = f >> 3;
                unsigned b = (unsigned)(LACT + row * 384 + (((c & 24) | ((c & 7) ^ (row & 7))) << 4) + (f & 7) * 2);
                *(unsigned short*)(smem + b) = f2bf(s * u);
            }
    asm volatile("s_waitcnt vmcnt(3) lgkmcnt(0)");   // B2(0) done; B2(1) in flight
    __builtin_amdgcn_s_barrier();
    __builtin_amdgcn_sched_barrier(0);

    // ================= GEMM2: out[128][768] = act[128][192] * down, 2-deep =================
    #pragma unroll
    for (int half = 0; half < 2; ++half) {
        f32x4 c2[4][6];
        #pragma unroll
        for (int mt = 0; mt < 4; ++mt)
            #pragma unroll
            for (int nt = 0; nt < 6; ++nt) c2[mt][nt] = fzero;

        #pragma unroll
        for (int kt = 0; kt < 6; ++kt) {
            const int s = half * 6 + kt;
            if (s < 10) {
                #pragma unroll
                for (int i = 0; i < 3; ++i)
                    GLL(gls2 + (size_t)(s + 2) * 12288 + i * 512, LCo[(s + 2) % 3] + gld + i * 1024u);
            }

            int c = kt * 4 + lg;
            unsigned a2sl = (unsigned)(((c & 24) | ((c & 7) ^ (l16 & 7))) << 4);
            bf16x8 A2[4];
            #pragma unroll
            for (int mt = 0; mt < 4; ++mt)
                A2[mt] = *(const bf16x8*)(smem + LACT + (rw64 + mt * 16 + l16) * 384 + a2sl);
            __builtin_amdgcn_s_setprio(1);
            #pragma unroll
            for (int nt = 0; nt < 6; ++nt) {
                bf16x8 B2f = *(const bf16x8*)(smem + LCo[s % 3] + b2rb[nt]);
                #pragma unroll
                for (int mt = 0; mt < 4; ++mt)
                    c2[mt][nt] = __builtin_amdgcn_mfma_f32_16x16x32_bf16(A2[mt], B2f, c2[mt][nt], 0, 0, 0);
            }
            __builtin_amdgcn_s_setprio(0);

            if (s < 11) {
                if (s < 10) asm volatile("s_waitcnt vmcnt(3) lgkmcnt(0)");
                else        asm volatile("s_waitcnt vmcnt(0) lgkmcnt(0)");
                __builtin_amdgcn_s_barrier();
                __builtin_amdgcn_sched_barrier(0);
            }
        }

        #pragma unroll
        for (int mt = 0; mt < 4; ++mt)
            #pragma unroll
            for (int p = 0; p < 4; ++p) {
                int row = rw64 + mt * 16 + 4 * lg + p;
                if (t0 + row < n_e) {
                    float* orow = out + (size_t)tokp[row] * HD + half * 384 + cq * 96 + l16;
                    #pragma unroll
                    for (int nt = 0; nt < 6; ++nt)
                        orow[nt * 16] = c2[mt][nt][p];
                }
            }
    }
}

extern "C" void kernel_launch(void* const* d_in, const int* in_sizes, int n_in,
                              void* d_out, int out_size, void* d_ws, size_t ws_size,
                              hipStream_t stream) {
    (void)in_sizes; (void)n_in; (void)out_size; (void)ws_size;
    const float* hidden = (const float*)d_in[0];
    const int*   ids    = (const int*)d_in[1];
    const float* gu     = (const float*)d_in[2];
    const float* dn     = (const float*)d_in[3];
    float* out = (float*)d_out;

    char* ws = (char*)d_ws;
    int* counts = (int*)ws;
    int* bucket = (int*)(ws + WS_BUCKET_OFF);
    unsigned short* b1img = (unsigned short*)(ws + WS_B1IMG_OFF);
    unsigned short* dnimg = (unsigned short*)(ws + WS_DNIMG_OFF);

    hipMemsetAsync(d_ws, 0, 64, stream);
    route_kernel<<<NT / 256, 256, 0, stream>>>(ids, counts, bucket);
    b1img_kernel<<<576, 256, 0, stream>>>(gu, b1img);       // NE*24*1536 units
    dnimg_kernel<<<288, 256, 0, stream>>>(dn, dnimg);       // NE*2*6*1536 units
    moe_kernel<<<1028, 512, SMEM_BYTES, stream>>>(hidden, counts, bucket, b1img, dnimg, out);
}